// Round 1
// baseline (21.641 us; speedup 1.0000x reference)
//
#include <hip/hip_runtime.h>

#define HIDDEN 768
#define LN_EPS 1e-5f

// One 64-lane wave per token row. Each lane handles 3 float4 (12 floats) of
// the 768-wide hidden dim: float4 index = lane + k*64, k in 0..2 (coalesced).
__global__ __launch_bounds__(256) void bert_embedding_kernel(
    const int* __restrict__ input_ids,
    const int* __restrict__ token_type_ids,
    const float* __restrict__ tok_w,
    const float* __restrict__ pos_w,
    const float* __restrict__ type_w,
    const float* __restrict__ gamma,
    const float* __restrict__ beta,
    float* __restrict__ out,
    int n_rows, int S)
{
    const int wave = (blockIdx.x * blockDim.x + threadIdx.x) >> 6;
    const int lane = threadIdx.x & 63;
    if (wave >= n_rows) return;

    const int s = wave % S;                 // position index
    const int tok = input_ids[wave];        // token id
    const int typ = token_type_ids[wave];   // segment id

    const float4* __restrict__ tw = reinterpret_cast<const float4*>(tok_w  + (size_t)tok * HIDDEN);
    const float4* __restrict__ pw = reinterpret_cast<const float4*>(pos_w  + (size_t)s   * HIDDEN);
    const float4* __restrict__ yw = reinterpret_cast<const float4*>(type_w + (size_t)typ * HIDDEN);

    float4 e[3];
    float sum = 0.f, sumsq = 0.f;
    #pragma unroll
    for (int k = 0; k < 3; ++k) {
        const int idx = lane + k * 64;
        const float4 a = tw[idx];
        const float4 b = pw[idx];
        const float4 c = yw[idx];
        float4 v;
        v.x = a.x + b.x + c.x;
        v.y = a.y + b.y + c.y;
        v.z = a.z + b.z + c.z;
        v.w = a.w + b.w + c.w;
        e[k] = v;
        sum   += v.x + v.y + v.z + v.w;
        sumsq += v.x * v.x + v.y * v.y + v.z * v.z + v.w * v.w;
    }

    // Wave-wide butterfly reduction (64 lanes).
    #pragma unroll
    for (int m = 1; m < 64; m <<= 1) {
        sum   += __shfl_xor(sum, m);
        sumsq += __shfl_xor(sumsq, m);
    }

    const float inv_h = 1.0f / (float)HIDDEN;
    const float mean = sum * inv_h;
    const float var  = sumsq * inv_h - mean * mean;
    const float rs   = rsqrtf(var + LN_EPS);

    float4* __restrict__ o = reinterpret_cast<float4*>(out + (size_t)wave * HIDDEN);
    const float4* __restrict__ g4 = reinterpret_cast<const float4*>(gamma);
    const float4* __restrict__ b4 = reinterpret_cast<const float4*>(beta);

    #pragma unroll
    for (int k = 0; k < 3; ++k) {
        const int idx = lane + k * 64;
        const float4 g = g4[idx];
        const float4 bb = b4[idx];
        const float4 v = e[k];
        float4 r;
        r.x = (v.x - mean) * rs * g.x + bb.x;
        r.y = (v.y - mean) * rs * g.y + bb.y;
        r.z = (v.z - mean) * rs * g.z + bb.z;
        r.w = (v.w - mean) * rs * g.w + bb.w;
        o[idx] = r;
    }
}

extern "C" void kernel_launch(void* const* d_in, const int* in_sizes, int n_in,
                              void* d_out, int out_size, void* d_ws, size_t ws_size,
                              hipStream_t stream) {
    const int*   input_ids      = (const int*)d_in[0];
    const int*   token_type_ids = (const int*)d_in[1];
    const float* tok_w          = (const float*)d_in[2];
    const float* pos_w          = (const float*)d_in[3];
    const float* type_w         = (const float*)d_in[4];
    const float* gamma          = (const float*)d_in[5];
    const float* beta           = (const float*)d_in[6];
    float* out = (float*)d_out;

    const int n_rows = in_sizes[0];          // B * S = 16384
    const int S = in_sizes[3] / HIDDEN;      // pos_w rows = 512

    const int waves_per_block = 4;           // 256 threads
    const int blocks = (n_rows + waves_per_block - 1) / waves_per_block;
    bert_embedding_kernel<<<blocks, 256, 0, stream>>>(
        input_ids, token_type_ids, tok_w, pos_w, type_w, gamma, beta,
        out, n_rows, S);
}

// Round 2
// 21.008 us; speedup vs baseline: 1.0301x; 1.0301x over previous
//
#include <hip/hip_runtime.h>

#define HIDDEN 768
#define LN_EPS 1e-5f

typedef float f32x4 __attribute__((ext_vector_type(4)));

// One 64-lane wave per token row. Each lane handles 3 float4 (12 floats) of
// the 768-wide hidden dim: float4 index = lane + k*64, k in 0..2 (coalesced).
// Output uses nontemporal stores so the 48 MB streaming write does not evict
// the 94 MB token table from L3 (keeps gather reads L3-resident).
__global__ __launch_bounds__(256) void bert_embedding_kernel(
    const int* __restrict__ input_ids,
    const int* __restrict__ token_type_ids,
    const float* __restrict__ tok_w,
    const float* __restrict__ pos_w,
    const float* __restrict__ type_w,
    const float* __restrict__ gamma,
    const float* __restrict__ beta,
    float* __restrict__ out,
    int n_rows, int S)
{
    const int wave = (blockIdx.x * blockDim.x + threadIdx.x) >> 6;
    const int lane = threadIdx.x & 63;
    if (wave >= n_rows) return;

    const int s = wave % S;                 // position index
    const int tok = input_ids[wave];        // token id
    const int typ = token_type_ids[wave];   // segment id

    const f32x4* __restrict__ tw = reinterpret_cast<const f32x4*>(tok_w  + (size_t)tok * HIDDEN);
    const f32x4* __restrict__ pw = reinterpret_cast<const f32x4*>(pos_w  + (size_t)s   * HIDDEN);
    const f32x4* __restrict__ yw = reinterpret_cast<const f32x4*>(type_w + (size_t)typ * HIDDEN);

    f32x4 e[3];
    float sum = 0.f, sumsq = 0.f;
    #pragma unroll
    for (int k = 0; k < 3; ++k) {
        const int idx = lane + k * 64;
        const f32x4 a = tw[idx];
        const f32x4 b = pw[idx];
        const f32x4 c = yw[idx];
        f32x4 v = a + b + c;
        e[k] = v;
        sum   += v.x + v.y + v.z + v.w;
        sumsq += v.x * v.x + v.y * v.y + v.z * v.z + v.w * v.w;
    }

    // Wave-wide butterfly reduction (64 lanes).
    #pragma unroll
    for (int m = 1; m < 64; m <<= 1) {
        sum   += __shfl_xor(sum, m);
        sumsq += __shfl_xor(sumsq, m);
    }

    const float inv_h = 1.0f / (float)HIDDEN;
    const float mean = sum * inv_h;
    const float var  = sumsq * inv_h - mean * mean;
    const float rs   = rsqrtf(var + LN_EPS);

    f32x4* __restrict__ o = reinterpret_cast<f32x4*>(out + (size_t)wave * HIDDEN);
    const f32x4* __restrict__ g4 = reinterpret_cast<const f32x4*>(gamma);
    const f32x4* __restrict__ b4 = reinterpret_cast<const f32x4*>(beta);

    #pragma unroll
    for (int k = 0; k < 3; ++k) {
        const int idx = lane + k * 64;
        const f32x4 g  = g4[idx];
        const f32x4 bb = b4[idx];
        const f32x4 v  = e[k];
        f32x4 r;
        r.x = (v.x - mean) * rs * g.x + bb.x;
        r.y = (v.y - mean) * rs * g.y + bb.y;
        r.z = (v.z - mean) * rs * g.z + bb.z;
        r.w = (v.w - mean) * rs * g.w + bb.w;
        __builtin_nontemporal_store(r, &o[idx]);
    }
}

extern "C" void kernel_launch(void* const* d_in, const int* in_sizes, int n_in,
                              void* d_out, int out_size, void* d_ws, size_t ws_size,
                              hipStream_t stream) {
    const int*   input_ids      = (const int*)d_in[0];
    const int*   token_type_ids = (const int*)d_in[1];
    const float* tok_w          = (const float*)d_in[2];
    const float* pos_w          = (const float*)d_in[3];
    const float* type_w         = (const float*)d_in[4];
    const float* gamma          = (const float*)d_in[5];
    const float* beta           = (const float*)d_in[6];
    float* out = (float*)d_out;

    const int n_rows = in_sizes[0];          // B * S = 16384
    const int S = in_sizes[3] / HIDDEN;      // pos_w rows = 512

    const int waves_per_block = 4;           // 256 threads
    const int blocks = (n_rows + waves_per_block - 1) / waves_per_block;
    bert_embedding_kernel<<<blocks, 256, 0, stream>>>(
        input_ids, token_type_ids, tok_w, pos_w, type_w, gamma, beta,
        out, n_rows, S);
}